// Round 5
// baseline (120.151 us; speedup 1.0000x reference)
//
#include <hip/hip_runtime.h>
#include <stdint.h>

#define VOCAB 21128
#define NUMC  53
#define EMB   128
#define SEQ   512
#define BATCH 512

typedef __bf16 bf16x8 __attribute__((ext_vector_type(8)));
typedef float f32x4 __attribute__((ext_vector_type(4)));

__device__ __forceinline__ unsigned int f2bf1(float f) {
    union { float f; unsigned int u; } v; v.f = f;
    return (v.u + 0x7FFFu + ((v.u >> 16) & 1u)) >> 16;
}
__device__ __forceinline__ unsigned int pack2(float a, float b) {
    return f2bf1(a) | (f2bf1(b) << 16);
}

// Prep (Wp only now): conv_w -> bf16 per-lane B-fragment order (16x16x32,
// verified r1-r10):
// Wp[s 0..11][g 0..7][lane 0..63][j 0..7] = w[f=g*16+(lane&15)][e=kk&127][tap=kk>>7],
// kk = s*32 + (lane>>4)*8 + j.
// r4 post-mortem: the embedding bf16 table (Tb) is GONE — gathering from a
// ws buffer that prep re-writes into freshly-poisoned memory every iteration
// kept the gather HBM-cold (r3: FETCH 135 MB, 2.2 TB/s, pipes <10%). The
// tile kernel now gathers straight from the iteration-stable, L3-resident
// emb input and converts in-register.
__global__ void prep_kernel(const float* __restrict__ cw, unsigned short* __restrict__ Wp) {
    int idx = blockIdx.x * blockDim.x + threadIdx.x;
    if (idx < 12 * 8 * 64 * 8) {
        int j = idx & 7, l = (idx >> 3) & 63, g = (idx >> 9) & 7, s = idx >> 12;
        int kk = s * 32 + (l >> 4) * 8 + j;
        int f = g * 16 + (l & 15);
        int tap = kk >> 7, e = kk & 127;
        Wp[idx] = (unsigned short)f2bf1(cw[(f * EMB + e) * 3 + tap]);
    }
}

// 4096 blocks: block (b, tq) = batch row b, positions [tq*64, tq*64+64).
// 256 threads = 4 waves; wave wn owns filter group [wn*32, wn*32+32), full
// M=64 (4 mt), acc[4][2]. Staging: reg-staged DIRECT gather from fp32 emb —
// per task (66 rows x 16 chunks = 1056): 32 B fp32 (2x dwordx4, all loads
// hoisted/in flight) -> f2bf1 pack (numerics identical to old prep) ->
// ds_write_b128. LDS layout unchanged from r0-r4: 66 rows x 256 B bf16,
// XOR swizzle on the SOURCE chunk index (LDS slot (r,c) holds global chunk
// c^(r&15)), so the MFMA-phase read path is byte-for-byte identical.
// launch_bounds(256,4): ~110 VGPR with 10 float4 of staging in flight;
// residency proven non-binding in r4 (6 blocks/CU == 4 blocks/CU).
__launch_bounds__(256, 4)
__global__ void pcnn_tile(const int* __restrict__ cid, const int* __restrict__ p1,
                          const int* __restrict__ p2,
                          const float* __restrict__ emb,
                          const unsigned short* __restrict__ Wp,
                          float* __restrict__ Pd) {
    __shared__ __align__(16) unsigned short xs[66 * 128];  // 16,896 B, unpadded

    const int bx   = blockIdx.x;
    const int b    = bx >> 3;
    const int tq   = bx & 7;
    const int tid  = threadIdx.x;
    const int lane = tid & 63;
    const int wn   = tid >> 6;   // 0..3 filter group (32 filters)
    const int quad = lane >> 4;
    const int lc   = lane & 15;

    const int* crow = cid + (size_t)b * SEQ;

    // ---- Stage: 1056 tasks; task=(r,c): row r <-> pos tq*64 + r - 1, c = 16 B
    // LDS chunk. OOB -> id 0 (emb row 0 is all zeros: padding_idx). Source =
    // 32 B of emb row id at fp32 chunk cs = c^(r&15); dest = linear LDS slot
    // task*16 after f2bf1 packing. i<4 always valid (task<=1023); i=4 tid<32.
    float4 ga[5], gb[5];
#pragma unroll
    for (int i = 0; i < 5; ++i) {
        int task = tid + 256 * i;
        if (i < 4 || tid < 32) {
            int r = task >> 4, c = task & 15;
            int p = tq * 64 + r - 1;
            unsigned int id = (p >= 0 && p < SEQ) ? (unsigned int)crow[p] : 0u;
            int cs = c ^ (r & 15);
            const float4* src = (const float4*)(emb + (size_t)id * EMB + cs * 8);
            ga[i] = src[0];
            gb[i] = src[1];
        }
    }
#pragma unroll
    for (int i = 0; i < 5; ++i) {
        int task = tid + 256 * i;
        if (i < 4 || tid < 32) {
            uint4 o;
            o.x = pack2(ga[i].x, ga[i].y);
            o.y = pack2(ga[i].z, ga[i].w);
            o.z = pack2(gb[i].x, gb[i].y);
            o.w = pack2(gb[i].z, gb[i].w);
            *(uint4*)((char*)xs + task * 16) = o;
        }
    }

    int e1 = min(p1[b], p2[b]);
    int e2 = max(p1[b], p2[b]);
    if (e1 == e2) e2 = min(e1 + 1, SEQ);
    const int e1m = max(e1, 1);

    __syncthreads();

    // ---- Conv via MFMA 16x16x32 bf16: M=64 (4 mt), N=32/wave (2 nt), K=384
    f32x4 acc[4][2];
#pragma unroll
    for (int mt = 0; mt < 4; ++mt)
#pragma unroll
        for (int nt = 0; nt < 2; ++nt)
            acc[mt][nt] = (f32x4){0.f, 0.f, 0.f, 0.f};

#pragma unroll
    for (int s = 0; s < 12; ++s) {
        const int tap = s >> 2;
        const int q   = (s & 3) * 4 + quad;             // global 16 B chunk wanted
        const int cs  = q ^ ((lc + tap) & 15);          // swizzled LDS chunk (= q^(r&15))
        bf16x8 b0 = *(const bf16x8*)(Wp + (size_t)((s * 8 + wn * 2) * 64 + lane) * 8);
        bf16x8 b1 = *(const bf16x8*)(Wp + (size_t)((s * 8 + wn * 2 + 1) * 64 + lane) * 8);
#pragma unroll
        for (int mt = 0; mt < 4; ++mt) {
            int r = mt * 16 + lc + tap;
            bf16x8 a = *(const bf16x8*)(xs + r * 128 + cs * 8);
            acc[mt][0] = __builtin_amdgcn_mfma_f32_16x16x32_bf16(a, b0, acc[mt][0], 0, 0, 0);
            acc[mt][1] = __builtin_amdgcn_mfma_f32_16x16x32_bf16(a, b1, acc[mt][1], 0, 0, 0);
        }
    }

    // ---- Piecewise max over this tile's 64 positions (raw conv; bias+relu in combine)
    float smax[3][2];
#pragma unroll
    for (int s3 = 0; s3 < 3; ++s3) { smax[s3][0] = -1e30f; smax[s3][1] = -1e30f; }

#pragma unroll
    for (int mt = 0; mt < 4; ++mt)
#pragma unroll
        for (int reg = 0; reg < 4; ++reg) {
            int p = tq * 64 + mt * 16 + quad * 4 + reg;
            float a0 = (p < e1m) ? 0.f : -2e30f;
            float a1 = (p >= e1 && p < e2) ? 0.f : -2e30f;
            float a2 = (p >= e2) ? 0.f : -2e30f;
#pragma unroll
            for (int nt = 0; nt < 2; ++nt) {
                float v = acc[mt][nt][reg];
                smax[0][nt] = fmaxf(smax[0][nt], v + a0);
                smax[1][nt] = fmaxf(smax[1][nt], v + a1);
                smax[2][nt] = fmaxf(smax[2][nt], v + a2);
            }
        }

    // Quad reduction in-register (butterfly over lanes ^16, ^32); lane<16
    // stores this block's partial directly (one M-group -> no cross-wave stage).
#pragma unroll
    for (int s3 = 0; s3 < 3; ++s3)
#pragma unroll
        for (int nt = 0; nt < 2; ++nt) {
            float v = smax[s3][nt];
            v = fmaxf(v, __shfl_xor(v, 16));
            v = fmaxf(v, __shfl_xor(v, 32));
            smax[s3][nt] = v;
        }
    if (lane < 16) {
        float* pd = Pd + ((size_t)b * 8 + tq) * 384;
#pragma unroll
        for (int s3 = 0; s3 < 3; ++s3)
#pragma unroll
            for (int nt = 0; nt < 2; ++nt)
                pd[s3 * 128 + wn * 32 + nt * 16 + lc] = smax[s3][nt];
    }
}

// Combine: max over the 8 tile-partials, bias+ReLU, FC 384->53. One block per row.
__launch_bounds__(256)
__global__ void pcnn_combine(const float* __restrict__ Pd, const float* __restrict__ cb,
                             const float* __restrict__ fcw, const float* __restrict__ fcb,
                             float* __restrict__ out) {
    __shared__ float pooled[384];
    __shared__ float fcred[NUMC][4];
    const int b = blockIdx.x;
    const int tid = threadIdx.x;

    for (int j = tid; j < 384; j += 256) {
        const float* pp = Pd + (size_t)b * 8 * 384 + j;
        float m0 = fmaxf(pp[0 * 384], pp[1 * 384]);
        float m1 = fmaxf(pp[2 * 384], pp[3 * 384]);
        float m2 = fmaxf(pp[4 * 384], pp[5 * 384]);
        float m3 = fmaxf(pp[6 * 384], pp[7 * 384]);
        float m = fmaxf(fmaxf(m0, m1), fmaxf(m2, m3));
        pooled[j] = fmaxf(m + cb[j & 127], 0.f);
    }
    __syncthreads();

    if (tid < 212) {
        int c = tid >> 2, q = tid & 3;
        const float* wrow = fcw + (size_t)c * 384 + q * 96;
        const float* pp   = pooled + q * 96;
        float sum = 0.f;
#pragma unroll 8
        for (int i = 0; i < 96; ++i) sum += wrow[i] * pp[i];
        fcred[c][q] = sum;
    }
    __syncthreads();
    if (tid < NUMC)
        out[(size_t)b * NUMC + tid] =
            fcred[tid][0] + fcred[tid][1] + fcred[tid][2] + fcred[tid][3] + fcb[tid];
}

extern "C" void kernel_launch(void* const* d_in, const int* in_sizes, int n_in,
                              void* d_out, int out_size, void* d_ws, size_t ws_size,
                              hipStream_t stream) {
    const int*   cid = (const int*)d_in[0];
    const int*   p1  = (const int*)d_in[1];
    const int*   p2  = (const int*)d_in[2];
    const float* emb = (const float*)d_in[3];
    const float* cw  = (const float*)d_in[4];
    const float* cb  = (const float*)d_in[5];
    const float* fcw = (const float*)d_in[6];
    const float* fcb = (const float*)d_in[7];
    float* out = (float*)d_out;

    // ws: Wp bf16 [49152] (98,304 B) | Pd fp32 [512*8*384] (6,291,456 B)
    unsigned short* Wp = (unsigned short*)d_ws;
    float*          Pd = (float*)((char*)d_ws + 98304);

    prep_kernel<<<192, 256, 0, stream>>>(cw, Wp);
    pcnn_tile<<<BATCH * 8, 256, 0, stream>>>(cid, p1, p2, emb, Wp, Pd);
    pcnn_combine<<<BATCH, 256, 0, stream>>>(Pd, cb, fcw, fcb, out);
}